// Round 2
// baseline (588.370 us; speedup 1.0000x reference)
//
#include <hip/hip_runtime.h>

#define B_  8
#define IB_ 1024
#define S_  4096
#define D_  512

typedef _Float16 f16;
typedef _Float16 f16x8 __attribute__((ext_vector_type(8)));
typedef _Float16 f16x4 __attribute__((ext_vector_type(4)));
typedef float    f32x4 __attribute__((ext_vector_type(4)));

// ---------------- async global->LDS, 16B per lane ----------------
__device__ __forceinline__ void gld_lds16(const f16* g, f16* l) {
  __builtin_amdgcn_global_load_lds(
      (const __attribute__((address_space(1))) void*)g,
      (__attribute__((address_space(3))) void*)l, 16, 0, 0);
}

// ---------------- generic C = A(M,K) * B(N,K)^T  (f16 in, f32 accum) -------
// 128x128 tile, BK=32, 256 threads = 4 waves (2x2), per-wave 64x64 via
// 4x4 x mfma_f32_16x16x32_f16. LDS linear (global_load_lds), source-side
// XOR swizzle (chunk ^= (row>>1)&3) so ds_read_b128 is ~2-way conflict-free.
// lda/ldb = element stride between rows of A / B (row-major).
__global__ __launch_bounds__(256) void gemm_bt(
    const f16* __restrict__ A, const f16* __restrict__ B,
    float* __restrict__ C32, f16* __restrict__ C16,
    int M, int N, int K, int lda, int ldb,
    long long sAb, long long sBb, long long sCb,
    const float* __restrict__ bias_row, const float* __restrict__ bias_col,
    float scale)
{
  __shared__ f16 ldsA[128 * 32];
  __shared__ f16 ldsB[128 * 32];
  const int tid  = threadIdx.x;
  const int lane = tid & 63;
  const int wave = tid >> 6;
  const int zb   = blockIdx.z;
  A += (size_t)zb * (size_t)sAb;
  B += (size_t)zb * (size_t)sBb;
  const int m0 = blockIdx.y * 128;
  const int n0 = blockIdx.x * 128;
  const int wm = wave >> 1, wn = wave & 1;

  f32x4 acc[4][4];
#pragma unroll
  for (int i = 0; i < 4; ++i)
#pragma unroll
    for (int j = 0; j < 4; ++j) acc[i][j] = (f32x4){0.f, 0.f, 0.f, 0.f};

  // per-lane fragment LDS element offsets (swizzled)
  int aoff[4], boff[4];
  const int cl = lane >> 4;
#pragma unroll
  for (int r = 0; r < 4; ++r) {
    int rowa = wm * 64 + r * 16 + (lane & 15);
    aoff[r] = rowa * 32 + (cl ^ ((rowa >> 1) & 3)) * 8;
    int rowb = wn * 64 + r * 16 + (lane & 15);
    boff[r] = rowb * 32 + (cl ^ ((rowb >> 1) & 3)) * 8;
  }
  // staging coords: 512 16B-chunks per tile, 2 per thread; physical chunk
  // (row,cp) holds global chunk cg = cp ^ ((row>>1)&3)
  int srow[2], scg[2];
#pragma unroll
  for (int it = 0; it < 2; ++it) {
    int ch = wave * 64 + it * 256 + lane;
    srow[it] = ch >> 2;
    scg[it]  = (ch & 3) ^ ((srow[it] >> 1) & 3);
  }

  for (int k0 = 0; k0 < K; k0 += 32) {
#pragma unroll
    for (int it = 0; it < 2; ++it) {
      gld_lds16(A + (size_t)(m0 + srow[it]) * (size_t)lda + (k0 + scg[it] * 8),
                &ldsA[(wave * 64 + it * 256) * 8]);
      gld_lds16(B + (size_t)(n0 + srow[it]) * (size_t)ldb + (k0 + scg[it] * 8),
                &ldsB[(wave * 64 + it * 256) * 8]);
    }
    __syncthreads();
    f16x8 af[4], bf[4];
#pragma unroll
    for (int r = 0; r < 4; ++r) af[r] = *(const f16x8*)&ldsA[aoff[r]];
#pragma unroll
    for (int r = 0; r < 4; ++r) bf[r] = *(const f16x8*)&ldsB[boff[r]];
#pragma unroll
    for (int mr = 0; mr < 4; ++mr)
#pragma unroll
      for (int nr = 0; nr < 4; ++nr)
        acc[mr][nr] = __builtin_amdgcn_mfma_f32_16x16x32_f16(
            af[mr], bf[nr], acc[mr][nr], 0, 0, 0);
    __syncthreads();
  }

  float* c32 = C32 ? C32 + (size_t)zb * (size_t)sCb : nullptr;
  f16*   c16 = C16 ? C16 + (size_t)zb * (size_t)sCb : nullptr;
  // C/D layout [m89]: col = lane&15, row = (lane>>4)*4 + reg
#pragma unroll
  for (int mr = 0; mr < 4; ++mr) {
#pragma unroll
    for (int r = 0; r < 4; ++r) {
      int grow = m0 + wm * 64 + mr * 16 + (lane >> 4) * 4 + r;
      float brv = bias_row ? bias_row[grow] : 0.f;
#pragma unroll
      for (int nr = 0; nr < 4; ++nr) {
        int gcol = n0 + wn * 64 + nr * 16 + (lane & 15);
        float v = acc[mr][nr][r] * scale + brv +
                  (bias_col ? bias_col[gcol] : 0.f);
        if (c32) c32[(size_t)grow * N + gcol] = v;
        else     c16[(size_t)grow * N + gcol] = (f16)v;
      }
    }
  }
}

// ---------------- f32 -> f16 ----------------
__global__ __launch_bounds__(256) void cvt_f32_to_f16(
    const float* __restrict__ in, f16* __restrict__ out, unsigned n)
{
  unsigned i = (blockIdx.x * 256u + threadIdx.x) * 4u;
  if (i >= n) return;
  const float4 v = *(const float4*)(in + i);
  f16x4 h;
  h[0] = (f16)v.x; h[1] = (f16)v.y; h[2] = (f16)v.z; h[3] = (f16)v.w;
  *(f16x4*)(out + i) = h;
}

// ---------------- row sums of Wb2s (S, IB): A[s] = sum_j W[s,j] ----------
__global__ __launch_bounds__(256) void rowsum_kernel(
    const float* __restrict__ W, float* __restrict__ out)
{
  int s = blockIdx.x;
  const float* row = W + (size_t)s * IB_;
  float acc = 0.f;
  for (int j = threadIdx.x; j < IB_; j += 256) acc += row[j];
  __shared__ float red[4];
#pragma unroll
  for (int o = 32; o >= 1; o >>= 1) acc += __shfl_xor(acc, o);
  if ((threadIdx.x & 63) == 0) red[threadIdx.x >> 6] = acc;
  __syncthreads();
  if (threadIdx.x == 0) out[s] = red[0] + red[1] + red[2] + red[3];
}

// ---------------- transpose Wb2s (S, IB) -> WT (IB, S), f32 --------------
__global__ __launch_bounds__(256) void transpose_f32(
    const float* __restrict__ in, float* __restrict__ out)
{
  __shared__ float t[32][33];
  int c0 = blockIdx.x * 32;          // col in 'in' (j)
  int r0 = blockIdx.y * 32;          // row in 'in' (s)
  int tx = threadIdx.x & 31, ty = threadIdx.x >> 5;
  for (int j = ty; j < 32; j += 8)
    t[j][tx] = in[(size_t)(r0 + j) * IB_ + c0 + tx];
  __syncthreads();
  for (int j = ty; j < 32; j += 8)
    out[(size_t)(c0 + j) * S_ + r0 + tx] = t[tx][j];
}

// ---------------- banded-softmax row + top-k(2050) -> sparse f16 ---------
__device__ __forceinline__ unsigned fkey(float x) {
  unsigned u = __float_as_uint(x);
  return (u & 0x80000000u) ? ~u : (u | 0x80000000u);
}

__global__ __launch_bounds__(256) void sparse_topk(
    const float* __restrict__ WT, const float* __restrict__ Acs,
    const float* __restrict__ bb2s, f16* __restrict__ sp)
{
  const int i = blockIdx.x;   // 0..IB-1
  __shared__ float vals[S_];
  __shared__ unsigned hist[256];
  __shared__ unsigned sprefix;
  __shared__ int srem;
  const float e1 = 2.71828182845904523536f;
  const int n1 = (i == 0 || i == IB_ - 1) ? 2 : 3;
  const float Z = (float)n1 * e1 + (float)(IB_ - n1);
  const float alpha = 1.f / Z;
  const float beta  = (e1 - 1.f) / Z;
  const float* wmid = WT + (size_t)i * S_;
  const float* wlo  = (i > 0)       ? WT + (size_t)(i - 1) * S_ : nullptr;
  const float* whi  = (i < IB_ - 1) ? WT + (size_t)(i + 1) * S_ : nullptr;
  for (int s = threadIdx.x; s < S_; s += 256) {
    float band = wmid[s];
    if (wlo) band += wlo[s];
    if (whi) band += whi[s];
    vals[s] = alpha * Acs[s] + beta * band + bb2s[s];
  }
  if (threadIdx.x == 0) { sprefix = 0u; srem = S_ / 2 + 2; }  // 2050
  __syncthreads();
  for (int shift = 24; shift >= 0; shift -= 8) {
    hist[threadIdx.x] = 0u;
    __syncthreads();
    unsigned pfx = sprefix;
    unsigned himask = (shift == 24) ? 0u : (0xFFFFFFFFu << (shift + 8));
    for (int s = threadIdx.x; s < S_; s += 256) {
      unsigned key = fkey(vals[s]);
      if ((key & himask) == (pfx & himask))
        atomicAdd(&hist[(key >> shift) & 255u], 1u);
    }
    __syncthreads();
    if (threadIdx.x == 0) {
      int rem = srem;
      unsigned acc = 0;
      int b = 255;
      for (; b > 0; --b) {
        unsigned c = hist[b];
        if (acc + c >= (unsigned)rem) break;
        acc += c;
      }
      sprefix = pfx | ((unsigned)b << shift);
      srem = rem - (int)acc;
    }
    __syncthreads();
  }
  const unsigned T = sprefix;
  for (int s = threadIdx.x; s < S_; s += 256) {
    float v = vals[s];
    sp[(size_t)i * S_ + s] = (fkey(v) >= T) ? (f16)v : (f16)0.f;
  }
}

// ---------------- row softmax (4096 f32) -> P f16 (row stride ostride) ---
__global__ __launch_bounds__(256) void softmax_rows(
    const float* __restrict__ L, f16* __restrict__ P, long long ostride)
{
  const size_t row = blockIdx.x;
  const float* in = L + row * S_;
  f16* out = P + row * (size_t)ostride;
  __shared__ float red[4];
  float4 v[4];
  float mx = -3.4e38f;
#pragma unroll
  for (int j = 0; j < 4; ++j) {
    v[j] = *(const float4*)(in + ((size_t)threadIdx.x + j * 256) * 4);
    mx = fmaxf(mx, fmaxf(fmaxf(v[j].x, v[j].y), fmaxf(v[j].z, v[j].w)));
  }
#pragma unroll
  for (int o = 32; o >= 1; o >>= 1) mx = fmaxf(mx, __shfl_xor(mx, o));
  if ((threadIdx.x & 63) == 0) red[threadIdx.x >> 6] = mx;
  __syncthreads();
  mx = fmaxf(fmaxf(red[0], red[1]), fmaxf(red[2], red[3]));
  __syncthreads();
  float sum = 0.f;
#pragma unroll
  for (int j = 0; j < 4; ++j) {
    v[j].x = __expf(v[j].x - mx); v[j].y = __expf(v[j].y - mx);
    v[j].z = __expf(v[j].z - mx); v[j].w = __expf(v[j].w - mx);
    sum += v[j].x + v[j].y + v[j].z + v[j].w;
  }
#pragma unroll
  for (int o = 32; o >= 1; o >>= 1) sum += __shfl_xor(sum, o);
  if ((threadIdx.x & 63) == 0) red[threadIdx.x >> 6] = sum;
  __syncthreads();
  sum = red[0] + red[1] + red[2] + red[3];
  const float inv = 1.f / sum;
#pragma unroll
  for (int j = 0; j < 4; ++j) {
    f16x4 h;
    h[0] = (f16)(v[j].x * inv); h[1] = (f16)(v[j].y * inv);
    h[2] = (f16)(v[j].z * inv); h[3] = (f16)(v[j].w * inv);
    *(f16x4*)(out + ((size_t)threadIdx.x + j * 256) * 4) = h;
  }
}

// =========================================================================
extern "C" void kernel_launch(void* const* d_in, const int* in_sizes, int n_in,
                              void* d_out, int out_size, void* d_ws, size_t ws_size,
                              hipStream_t stream)
{
  const float* text = (const float*)d_in[0];   // (B,S,D)
  const float* img  = (const float*)d_in[1];   // (B,IB,D)
  const float* Wq   = (const float*)d_in[2];
  const float* bq   = (const float*)d_in[3];
  const float* Wk   = (const float*)d_in[4];
  const float* bk   = (const float*)d_in[5];
  const float* Wv   = (const float*)d_in[6];
  const float* bv   = (const float*)d_in[7];
  const float* Wb2s = (const float*)d_in[8];   // (S,IB)
  const float* bb2s = (const float*)d_in[9];   // (S,)
  float* outp = (float*)d_out;
  char* ws = (char*)d_ws;

  const long long SD = (long long)S_ * D_;     // 2,097,152
  const long long DS = (long long)D_ * S_;
  const long long DI = (long long)D_ * IB_;    //   524,288
  const long long IS = (long long)IB_ * S_;    // 4,194,304
  const long long ID = (long long)IB_ * D_;    //   524,288

  const size_t NEED_FAST = 209715200ull;       // 200 MiB
  const size_t NEED_PB   = 119029760ull;       // ~113.5 MiB
  const bool fast = ws_size >= NEED_FAST;
  if (!fast && ws_size < NEED_PB) return;      // learn: ws < 113.5 MiB

  // d_out doubles as scratch for sparse (8M) + W16 (8M); both dead before
  // the final GEMM writes d_out.
  f16* sparse = (f16*)d_out;                   // IB*S f16 = 8 MiB
  f16* W16    = (f16*)((char*)d_out + 8388608);// S*IB f16 = 8 MiB

  f16 *text16, *kT, *img16, *wq16, *wk16, *wv16, *MT, *qb, *Nb, *vT;
  float *WTf, *Acs, *logits;
  if (fast) {
    // logits f32 (128M) at 0 aliases all early-dead tenants:
    logits = (float*)(ws + 0);
    text16 = (f16*)(ws + 0);                   // 32M, dead after v-GEMM
    kT     = (f16*)(ws + 33554432ull);         // 32M, dead after MT-GEMM
    WTf    = (float*)(ws + 67108864ull);       // 16M, dead after topk
    img16  = (f16*)(ws + 83886080ull);         //  8M, dead after q-GEMM
    MT     = (f16*)(ws + 92274688ull);         //  8M, dead after N-GEMM
    wq16   = (f16*)(ws + 100663296ull);        // 1.5M total, dead after step 5
    wk16   = wq16 + 262144; wv16 = wk16 + 262144;
    Acs    = (float*)(ws + 102236160ull);      // 16K, dead after topk
    vT     = (f16*)(ws + 134217728ull);        // 32M, live to the end
    qb     = (f16*)(ws + 167772160ull);        //  8M
    Nb     = (f16*)(ws + 176160768ull);        // 32M
  } else {
    // region C (32M): WTf|img16 -> kT -> logits_b|P_b
    WTf    = (float*)(ws + 0);                 // 16M
    img16  = (f16*)(ws + 16777216ull);         //  8M
    kT     = (f16*)(ws + 0);                   // 32M (after topk + q-GEMM)
    logits = (float*)(ws + 0);                 // 16M per batch (after MT-GEMM)
    text16 = (f16*)(ws + 33554432ull);         // 32M -> Nb
    Nb     = (f16*)(ws + 33554432ull);
    vT     = (f16*)(ws + 67108864ull);         // 32M
    MT     = (f16*)(ws + 100663296ull);        //  8M
    qb     = (f16*)(ws + 109051904ull);        //  8M
    wq16   = (f16*)(ws + 117440512ull);
    wk16   = wq16 + 262144; wv16 = wk16 + 262144;
    Acs    = (float*)(ws + 119013376ull);
  }
  f16* Ppb = (f16*)(ws + 16777216ull);         // per-batch P (8M), region C

  dim3 blk(256);

  // 1) f32 -> f16 conversions (order matters for aliasing: see regions)
  cvt_f32_to_f16<<<(B_*IB_*D_)/1024, blk, 0, stream>>>(img, img16, B_*IB_*D_);
  cvt_f32_to_f16<<<(B_*S_*D_)/1024, blk, 0, stream>>>(text, text16, B_*S_*D_);
  cvt_f32_to_f16<<<(D_*D_)/1024, blk, 0, stream>>>(Wq, wq16, D_*D_);
  cvt_f32_to_f16<<<(D_*D_)/1024, blk, 0, stream>>>(Wk, wk16, D_*D_);
  cvt_f32_to_f16<<<(D_*D_)/1024, blk, 0, stream>>>(Wv, wv16, D_*D_);
  cvt_f32_to_f16<<<(S_*IB_)/1024, blk, 0, stream>>>(Wb2s, W16, S_*IB_);

  // 2) batch-invariant sparse pattern (before kT overwrites WTf region)
  rowsum_kernel<<<S_, blk, 0, stream>>>(Wb2s, Acs);
  transpose_f32<<<dim3(IB_/32, S_/32), blk, 0, stream>>>(Wb2s, WTf);
  sparse_topk<<<IB_, blk, 0, stream>>>(WTf, Acs, bb2s, sparse);

  // 3) q = img @ Wq^T + bq : (B*IB, D) f16   (before kT overwrites img16)
  gemm_bt<<<dim3(D_/128, (B_*IB_)/128, 1), blk, 0, stream>>>(
      img16, wq16, nullptr, qb, B_*IB_, D_, D_, D_, D_,
      0, 0, 0, nullptr, bq, 1.f);
  // 4) kT_b = Wk @ text_b^T + bk : (D, S) x B
  gemm_bt<<<dim3(S_/128, D_/128, B_), blk, 0, stream>>>(
      wk16, text16, nullptr, kT, D_, S_, D_, D_, D_,
      0, SD, DS, bk, nullptr, 1.f);
  // 5) vT_b = Wv @ text_b^T + bv
  gemm_bt<<<dim3(S_/128, D_/128, B_), blk, 0, stream>>>(
      wv16, text16, nullptr, vT, D_, S_, D_, D_, D_,
      0, SD, DS, bv, nullptr, 1.f);
  // 6) MT_b = kT_b @ sparse^T : (D, IB) x B
  gemm_bt<<<dim3(IB_/128, D_/128, B_), blk, 0, stream>>>(
      kT, sparse, nullptr, MT, D_, IB_, S_, S_, S_,
      DS, 0, DI, nullptr, nullptr, 1.f);
  // 7) N_b = Wb2s @ MT_b^T : (S, D) x B   (overwrites text16 region)
  gemm_bt<<<dim3(D_/128, S_/128, B_), blk, 0, stream>>>(
      W16, MT, nullptr, Nb, S_, D_, IB_, IB_, IB_,
      0, DI, SD, nullptr, nullptr, 1.f);

  const float scl = 0.04419417382415922f;  // 1/sqrt(512)
  if (fast) {
    // 8) logits_b = q_b @ N_b^T * scl + bb2s : (IB, S) f32 x B
    gemm_bt<<<dim3(S_/128, IB_/128, B_), blk, 0, stream>>>(
        qb, Nb, logits, nullptr, IB_, S_, D_, D_, D_,
        ID, SD, IS, nullptr, bb2s, scl);
    // 9) row softmax -> P f16, in-place into each row's own f32 storage
    softmax_rows<<<B_*IB_, blk, 0, stream>>>(logits, (f16*)logits, 2*S_);
    // 10) out_b = P_b @ vT_b^T : (IB, D) f32 x B  -> d_out
    gemm_bt<<<dim3(D_/128, IB_/128, B_), blk, 0, stream>>>(
        (f16*)logits, vT, outp, nullptr, IB_, D_, S_, 2*S_, S_,
        (long long)IB_*2*S_, DS, ID, nullptr, nullptr, 1.f);
  } else {
    for (int b = 0; b < B_; ++b) {
      gemm_bt<<<dim3(S_/128, IB_/128, 1), blk, 0, stream>>>(
          qb + (size_t)b*ID, Nb + (size_t)b*SD, logits, nullptr,
          IB_, S_, D_, D_, D_, 0, 0, 0, nullptr, bb2s, scl);
      softmax_rows<<<IB_, blk, 0, stream>>>(logits, Ppb, S_);
      gemm_bt<<<dim3(D_/128, IB_/128, 1), blk, 0, stream>>>(
          Ppb, vT + (size_t)b*DS, outp + (size_t)b*ID, nullptr,
          IB_, D_, S_, S_, S_, 0, 0, 0, nullptr, nullptr, 1.f);
    }
  }
}